// Round 14
// baseline (593.182 us; speedup 1.0000x reference)
//
#include <hip/hip_runtime.h>
#include <hip/hip_bf16.h>
#include <stdint.h>

// ---------------------------------------------------------------------------
// RegressionNet: cost-volume + 3x conv-BN-relu + 2x FC, bf16 MFMA pipeline.
// R13: convs -> BM=128 x BN=128 tiles, grid 512, 64KB LDS, acc[4][2],
//      __launch_bounds__(512,4) => 2 blocks/CU (TLP hides the tile-end
//      vmcnt(0) drain). Same fused-BN-stats template otherwise. fc1
//      pipelined (R12), l2norm reg-cached (R12).
// ---------------------------------------------------------------------------

typedef unsigned short ushort_t;
typedef __attribute__((ext_vector_type(8))) short     bf16x8;
typedef __attribute__((ext_vector_type(8))) unsigned short u16x8;
typedef __attribute__((ext_vector_type(2))) unsigned short u16x2;
typedef __attribute__((ext_vector_type(4))) float     f32x4;

#define NB   64
#define NC   256
#define NP   256
#define KP1  1152
#define NOUT 512
#define NROWS 16384
#define KFC  131072
#define NF   1024
#define KSPL 32      // fc1 k-splits

__device__ __forceinline__ unsigned short f2bf(float x) {
  union { float f; unsigned u; } c; c.f = x;
  unsigned r = c.u + 0x7FFFu + ((c.u >> 16) & 1u);
  return (unsigned short)(r >> 16);
}
__device__ __forceinline__ float b2f(unsigned short u) {
  union { unsigned u; float f; } c; c.u = ((unsigned)u) << 16; return c.f;
}

__device__ __forceinline__ void gl_lds16(const void* g, void* l) {
  __builtin_amdgcn_global_load_lds(
      (const __attribute__((address_space(1))) unsigned int*)g,
      (__attribute__((address_space(3))) unsigned int*)l, 16, 0, 0);
}

__device__ __forceinline__ f32x4 mfma16(bf16x8 a, bf16x8 b, f32x4 c) {
  return __builtin_amdgcn_mfma_f32_16x16x32_bf16(a, b, c, 0, 0, 0);
}

// ---------------------------------------------------------------------------
// l2-normalize over channels; write pos-major bf16 [b][pos][c].
// ---------------------------------------------------------------------------
__global__ __launch_bounds__(1024) void l2norm_t(
    const float* __restrict__ f1, const float* __restrict__ f2,
    ushort_t* __restrict__ AT, ushort_t* __restrict__ N2T)
{
  __shared__ float red[4][256];
  const float* src = blockIdx.y ? f2 : f1;
  ushort_t*    dst = blockIdx.y ? N2T : AT;
  const int b = blockIdx.x;
  const int pos = threadIdx.x & 255, q = threadIdx.x >> 8;
  const float* sb = src + (size_t)b * NC * NP;
  float v[64];
#pragma unroll
  for (int k = 0; k < 64; ++k) v[k] = sb[(q * 64 + k) * NP + pos];
  float sq = 0.f;
#pragma unroll
  for (int k = 0; k < 64; ++k) sq += v[k] * v[k];
  red[q][pos] = sq;
  __syncthreads();
  float tot = red[0][pos] + red[1][pos] + red[2][pos] + red[3][pos];
  float sc = 1.f / fmaxf(sqrtf(tot), 1e-12f);
  ushort_t* db = dst + ((size_t)b * NP + pos) * NC;
#pragma unroll
  for (int j = 0; j < 8; ++j) {
    u16x8 pk;
#pragma unroll
    for (int k = 0; k < 8; ++k) pk[k] = f2bf(v[j * 8 + k] * sc);
    *(u16x8*)(db + q * 64 + j * 8) = pk;
  }
}

// ---------------------------------------------------------------------------
// Pack all three conv weights in one launch.
// ---------------------------------------------------------------------------
#define T1P (9 * NOUT * KP1)
#define T23 (9 * NOUT * 512)
__global__ __launch_bounds__(256) void pack_all(
    const float* __restrict__ W1, const float* __restrict__ W2,
    const float* __restrict__ W3, ushort_t* __restrict__ Wp1,
    ushort_t* __restrict__ Wp2, ushort_t* __restrict__ Wp3)
{
  int p = blockIdx.x * 256 + threadIdx.x;
  const float* W; ushort_t* Wp; int Cin, Kp, q;
  if (p < T1P)            { W = W1; Wp = Wp1; Cin = 1089; Kp = KP1; q = p; }
  else if (p < T1P + T23) { W = W2; Wp = Wp2; Cin = 512;  Kp = 512; q = p - T1P; }
  else if (p < T1P + 2 * T23) { W = W3; Wp = Wp3; Cin = 512; Kp = 512; q = p - T1P - T23; }
  else return;
  int tap = q / (NOUT * Kp);
  int rem = q - tap * (NOUT * Kp);
  int o   = rem / Kp;
  int cin = rem - o * Kp;
  float v = (cin < Cin) ? W[((size_t)o * Cin + cin) * 9 + tap] : 0.f;
  Wp[q] = f2bf(v);
}

// ---------------------------------------------------------------------------
// Correlation GEMM: C[b][p][q] = sum_c AT[b][p][c] * N2T[b][q][c].
// ---------------------------------------------------------------------------
__global__ __launch_bounds__(256) void corr_gemm(
    const ushort_t* __restrict__ AT,
    const ushort_t* __restrict__ N2T,
    float* __restrict__ C)
{
  __shared__ ushort_t As[128 * 64];
  __shared__ ushort_t Bs[128 * 64];
  const int tid = threadIdx.x, lane = tid & 63, wave = tid >> 6;
  const int wr = wave >> 1, wc = wave & 1;
  const int la = lane & 15, lb = lane >> 4;
  const int b  = blockIdx.z;
  const int m0 = blockIdx.y * 128;
  const int n0 = blockIdx.x * 128;

  f32x4 acc[4][4];
#pragma unroll
  for (int i = 0; i < 4; ++i)
#pragma unroll
    for (int j = 0; j < 4; ++j) acc[i][j] = (f32x4){0.f, 0.f, 0.f, 0.f};

  const ushort_t* srcA[4];
  const ushort_t* srcB[4];
#pragma unroll
  for (int s = 0; s < 4; ++s) {
    int idx = tid + (s << 8);
    int row = idx >> 3, c16 = idx & 7;
    srcA[s] = AT  + ((size_t)b * NP + m0 + row) * NC + c16 * 8;
    srcB[s] = N2T + ((size_t)b * NP + n0 + row) * NC + c16 * 8;
  }

  for (int kc = 0; kc < NC; kc += 64) {
#pragma unroll
    for (int s = 0; s < 4; ++s) {
      int idx = tid + (s << 8);
      gl_lds16(srcA[s] + kc, &As[idx * 8]);
      gl_lds16(srcB[s] + kc, &Bs[idx * 8]);
    }
    __syncthreads();
#pragma unroll
    for (int kk = 0; kk < 2; ++kk) {
      bf16x8 af[4], bfv[4];
#pragma unroll
      for (int mi = 0; mi < 4; ++mi)
        af[mi] = *(const bf16x8*)&As[(wr * 64 + mi * 16 + la) * 64 + kk * 32 + lb * 8];
#pragma unroll
      for (int ni = 0; ni < 4; ++ni)
        bfv[ni] = *(const bf16x8*)&Bs[(wc * 64 + ni * 16 + la) * 64 + kk * 32 + lb * 8];
#pragma unroll
      for (int mi = 0; mi < 4; ++mi)
#pragma unroll
        for (int ni = 0; ni < 4; ++ni)
          acc[mi][ni] = mfma16(af[mi], bfv[ni], acc[mi][ni]);
    }
    __syncthreads();
  }

#pragma unroll
  for (int ni = 0; ni < 4; ++ni) {
    int col = n0 + wc * 64 + ni * 16 + la;
#pragma unroll
    for (int mi = 0; mi < 4; ++mi) {
      int p = m0 + wr * 64 + mi * 16 + lb * 4;
#pragma unroll
      for (int r = 0; r < 4; ++r)
        C[((size_t)b * NP + p + r) * NP + col] = acc[mi][ni][r];
    }
  }
}

// ---------------------------------------------------------------------------
// Cost write: expand C[b][ij][256] -> costT[b][ij][1152].
// ---------------------------------------------------------------------------
__global__ __launch_bounds__(576) void cost_write(
    const float* __restrict__ C, ushort_t* __restrict__ costT)
{
  __shared__ float row[256];
  const int ij = blockIdx.x, b = blockIdx.y, tid = threadIdx.x;
  const float* cr = C + ((size_t)b * NP + ij) * NP;
  if (tid < 256) row[tid] = cr[tid];
  __syncthreads();
  const int i = ij >> 4, j = ij & 15;
  const int d0 = tid * 2;
  u16x2 pk;
#pragma unroll
  for (int q = 0; q < 2; ++q) {
    int dd = d0 + q;
    int dy = dd / 33;
    int dx = dd - dy * 33;
    int oi = dy + i - 16, oj = dx + j - 16;
    float v = 0.f;
    if (((unsigned)oi < 16u) & ((unsigned)oj < 16u))
      v = row[oi * 16 + oj] * (1.f / 256.f);
    v = v > 0.f ? v : 0.01f * v;
    pk[q] = f2bf(v);
  }
  *(u16x2*)(costT + ((size_t)b * NP + ij) * KP1 + d0) = pk;
}

// ---------------------------------------------------------------------------
// Conv (all layers): BM=128, BN=128, fused BN stats. Block 512 = 8 waves
// (2M x 4N), per-wave 64x32 (acc[4][2], 32 VGPR). LDS dbuf 2x(A16K+B16K)
// = 64KB => 2 blocks/CU at __launch_bounds__(512,4). grid 512 (XCD swz).
// Per tile: P0 {read A01+B, stage next A0 A1} P1 {read A23, stage next
// B0 B1, vmcnt(0)}. Tile-end drain hidden by the co-resident block.
// ---------------------------------------------------------------------------
__global__ __launch_bounds__(512, 4) void conv_fused(
    const ushort_t* __restrict__ X, const ushort_t* __restrict__ Wp,
    const float* __restrict__ bias, ushort_t* __restrict__ Y,
    float* __restrict__ st, const int K, const int TPT, const int NT,
    const ushort_t* __restrict__ zerot)
{
  __shared__ ushort_t lds[2 * 16384];   // per buf: A[0,8192) B[8192,16384) elems
  const int tid = threadIdx.x;
  const int lane = tid & 63, wave = tid >> 6;
  const int wr = wave >> 2, wc = wave & 3;
  const int la = lane & 15, lb = lane >> 4;

  // XCD swizzle (512 blocks): L -> b, mh, n0
  const int bid = blockIdx.x;
  const int L = ((bid & 7) << 6) + (bid >> 3);
  const int b  = L >> 3;
  const int mh = (L >> 2) & 1;
  const int n0 = (L & 3) << 7;

  int amask[2];
  const ushort_t* abase[2];
  const ushort_t* bbase[2];
#pragma unroll
  for (int s = 0; s < 2; ++s) {
    int idx = tid + (s << 9);
    int ks = idx & 7, row = idx >> 3;          // row in 0..127
    int pos = mh * 128 + row;
    int i = pos >> 4, j = pos & 15;
    int m = 0;
#pragma unroll
    for (int tap = 0; tap < 9; ++tap) {
      int i2 = i + tap / 3 - 1, j2 = j + tap % 3 - 1;
      if (((unsigned)i2 < 16u) & ((unsigned)j2 < 16u)) m |= 1 << tap;
    }
    amask[s] = m;
    abase[s] = X + (size_t)(b * NP + pos) * K + ((ks ^ (row & 7)) << 3);
    int rB = (s << 6) + row - (s << 6);        // rB = row (slots are rows 0-63 / 64-127)
    rB = row;                                   // idx>>3 already spans 0..127 across s
    bbase[s] = Wp + (size_t)(n0 + rB) * K + ((ks ^ (rB & 7)) << 3);
  }

  const int ck0 = ((0 + lb) ^ (la & 7)) << 3;
  const int ck1 = (((4 + lb)) ^ (la & 7)) << 3;
  const int a_base = wr * 4096 + la * 64;            // + mi*1024
  const int b_off  = 8192 + (wc * 32 + la) * 64;     // + ni*1024

  f32x4 acc[4][2];
#pragma unroll
  for (int i = 0; i < 4; ++i)
#pragma unroll
    for (int j = 0; j < 2; ++j) acc[i][j] = (f32x4){0.f, 0.f, 0.f, 0.f};

  auto tile_par = [&](int tg, int& toffA, size_t& wtap, int& tap) {
    tap = tg / TPT;
    int kc = (tg - tap * TPT) << 6;
    int ty = tap / 3;
    toffA = (ty * 16 + (tap - 3 * ty) - 17) * K + kc;
    wtap  = (size_t)tap * NOUT * K + kc;
  };

#define FSTAGE_A(S) { const ushort_t* gp = ((amask[S] >> tapN) & 1) ? abase[S] + toffN : zerot; \
                      gl_lds16(gp, &bufn[(tid + ((S) << 9)) * 8]); }
#define FSTAGE_B(S) gl_lds16(bbase[S] + wtapN, &bufn[8192 + (tid + ((S) << 9)) * 8]);
#define FREAD_A01() \
  Af[0][0] = *(const bf16x8*)&buf[a_base + 0    + ck0]; Af[0][1] = *(const bf16x8*)&buf[a_base + 0    + ck1]; \
  Af[1][0] = *(const bf16x8*)&buf[a_base + 1024 + ck0]; Af[1][1] = *(const bf16x8*)&buf[a_base + 1024 + ck1];
#define FREAD_A23() \
  Af[0][0] = *(const bf16x8*)&buf[a_base + 2048 + ck0]; Af[0][1] = *(const bf16x8*)&buf[a_base + 2048 + ck1]; \
  Af[1][0] = *(const bf16x8*)&buf[a_base + 3072 + ck0]; Af[1][1] = *(const bf16x8*)&buf[a_base + 3072 + ck1];
#define FREAD_B() \
  Bf[0][0] = *(const bf16x8*)&buf[b_off + 0    + ck0]; Bf[0][1] = *(const bf16x8*)&buf[b_off + 0    + ck1]; \
  Bf[1][0] = *(const bf16x8*)&buf[b_off + 1024 + ck0]; Bf[1][1] = *(const bf16x8*)&buf[b_off + 1024 + ck1];
#define FMFMA(AB) \
  acc[(AB)+0][0] = mfma16(Af[0][0], Bf[0][0], acc[(AB)+0][0]); \
  acc[(AB)+0][1] = mfma16(Af[0][0], Bf[1][0], acc[(AB)+0][1]); \
  acc[(AB)+1][0] = mfma16(Af[1][0], Bf[0][0], acc[(AB)+1][0]); \
  acc[(AB)+1][1] = mfma16(Af[1][0], Bf[1][0], acc[(AB)+1][1]); \
  acc[(AB)+0][0] = mfma16(Af[0][1], Bf[0][1], acc[(AB)+0][0]); \
  acc[(AB)+0][1] = mfma16(Af[0][1], Bf[1][1], acc[(AB)+0][1]); \
  acc[(AB)+1][0] = mfma16(Af[1][1], Bf[0][1], acc[(AB)+1][0]); \
  acc[(AB)+1][1] = mfma16(Af[1][1], Bf[1][1], acc[(AB)+1][1]);

  // prologue: stage tile 0 fully
  {
    ushort_t* bufn = &lds[0];
    int tapN, toffN; size_t wtapN;
    tile_par(0, toffN, wtapN, tapN);
    FSTAGE_A(0) FSTAGE_A(1) FSTAGE_B(0) FSTAGE_B(1)
  }
  asm volatile("s_waitcnt vmcnt(0)" ::: "memory");
  __builtin_amdgcn_s_barrier();

  for (int t = 0; t < NT - 1; ++t) {
    const ushort_t* buf = &lds[(t & 1) * 16384];
    ushort_t* bufn = &lds[((t + 1) & 1) * 16384];
    int tapN, toffN; size_t wtapN;
    tile_par(t + 1, toffN, wtapN, tapN);
    bf16x8 Af[2][2], Bf[2][2];

    // P0: read A01 + B; stage next A0,A1
    FREAD_A01()
    FREAD_B()
    FSTAGE_A(0) FSTAGE_A(1)
    __builtin_amdgcn_s_barrier();
    asm volatile("s_waitcnt lgkmcnt(0)" ::: "memory");
    __builtin_amdgcn_sched_barrier(0);
    __builtin_amdgcn_s_setprio(1);
    FMFMA(0)
    __builtin_amdgcn_s_setprio(0);

    // P1: read A23; stage next B0,B1; tile-end drain
    FREAD_A23()
    FSTAGE_B(0) FSTAGE_B(1)
    asm volatile("s_waitcnt vmcnt(0)" ::: "memory");
    __builtin_amdgcn_s_barrier();
    asm volatile("s_waitcnt lgkmcnt(0)" ::: "memory");
    __builtin_amdgcn_sched_barrier(0);
    __builtin_amdgcn_s_setprio(1);
    FMFMA(2)
    __builtin_amdgcn_s_setprio(0);
    __builtin_amdgcn_s_barrier();
  }

  // tail tile
  {
    const ushort_t* buf = &lds[((NT - 1) & 1) * 16384];
    bf16x8 Af[2][2], Bf[2][2];
    FREAD_A01()
    FREAD_B()
    asm volatile("s_waitcnt lgkmcnt(0)" ::: "memory");
    __builtin_amdgcn_sched_barrier(0);
    FMFMA(0)
    FREAD_A23()
    asm volatile("s_waitcnt lgkmcnt(0)" ::: "memory");
    __builtin_amdgcn_sched_barrier(0);
    FMFMA(2)
  }

  // epilogue: bias + bf16 Y + fused BN stats
#pragma unroll
  for (int ni = 0; ni < 2; ++ni) {
    int col = n0 + wc * 32 + ni * 16 + la;
    float bv = bias[col];
    float s = 0.f, qq = 0.f;
#pragma unroll
    for (int mi = 0; mi < 4; ++mi) {
      int row = b * NP + mh * 128 + wr * 64 + mi * 16 + lb * 4;
#pragma unroll
      for (int r = 0; r < 4; ++r) {
        float v = acc[mi][ni][r] + bv;
        Y[(size_t)(row + r) * NOUT + col] = f2bf(v);
        s += v; qq += v * v;
      }
    }
    s  += __shfl_xor(s, 16);  s  += __shfl_xor(s, 32);
    qq += __shfl_xor(qq, 16); qq += __shfl_xor(qq, 32);
    if (lb == 0) {
      atomicAdd(&st[col], s);
      atomicAdd(&st[512 + col], qq);
    }
  }
#undef FSTAGE_A
#undef FSTAGE_B
#undef FREAD_A01
#undef FREAD_A23
#undef FREAD_B
#undef FMFMA
}

// ---------------------------------------------------------------------------
// BN apply (single Y) + relu + bf16, [m][c]. grid 4096, block 256.
// ---------------------------------------------------------------------------
__global__ __launch_bounds__(256) void bn_apply_s(
    const ushort_t* __restrict__ Y, const float* __restrict__ st,
    const float* __restrict__ g, const float* __restrict__ be,
    ushort_t* __restrict__ Xo)
{
  const size_t idx = (size_t)blockIdx.x * 256 + threadIdx.x;
  u16x8 a = *(const u16x8*)(Y + idx * 8);
  const int c0 = (int)((idx * 8) & 511);
  u16x8 pk;
#pragma unroll
  for (int q = 0; q < 8; ++q) {
    int cc = c0 + q;
    float y = b2f(a[q]);
    float mu  = st[cc] * (1.f / 16384.f);
    float var = st[512 + cc] * (1.f / 16384.f) - mu * mu;
    float s = rsqrtf(var + 1e-5f) * g[cc];
    pk[q] = f2bf(fmaxf((y - mu) * s + be[cc], 0.f));
  }
  *(u16x8*)(Xo + idx * 8) = pk;
}

// ---------------------------------------------------------------------------
// BN apply (single Y) + relu + bf16, transposed to Xf[b][c*256+ij].
// ---------------------------------------------------------------------------
__global__ __launch_bounds__(256) void bn_apply_ts(
    const ushort_t* __restrict__ Y, const float* __restrict__ st,
    const float* __restrict__ g, const float* __restrict__ be,
    ushort_t* __restrict__ Xf)
{
  __shared__ ushort_t T[64][65];
  const int c0  = blockIdx.x * 64;
  const int ij0 = blockIdx.y * 64;
  const int b   = blockIdx.z;
  const int tid = threadIdx.x;

#pragma unroll
  for (int it = 0; it < 16; ++it) {
    int e = it * 256 + tid;
    int ij = e >> 6, c = e & 63;
    int cg = c0 + c;
    float y = b2f(Y[((size_t)(b * NP + ij0 + ij)) * NOUT + cg]);
    float mu  = st[cg] * (1.f / 16384.f);
    float var = st[512 + cg] * (1.f / 16384.f) - mu * mu;
    float s = rsqrtf(var + 1e-5f) * g[cg];
    T[ij][c] = f2bf(fmaxf((y - mu) * s + be[cg], 0.f));
  }
  __syncthreads();
#pragma unroll
  for (int it = 0; it < 16; ++it) {
    int e = it * 256 + tid;
    int cr = e >> 6, ijc = e & 63;
    Xf[(size_t)b * KFC + (size_t)(c0 + cr) * NP + ij0 + ijc] = T[ijc][cr];
  }
}

// ---------------------------------------------------------------------------
// FC1: (64 x 131072) bf16 @ (1024 x 131072)^T, split-K slice stores.
// Software-pipelined (R12). grid (16, 32), block 256.
// ---------------------------------------------------------------------------
__device__ __forceinline__ u16x8 pack8(float4 a, float4 b) {
  u16x8 r;
  r[0] = f2bf(a.x); r[1] = f2bf(a.y); r[2] = f2bf(a.z); r[3] = f2bf(a.w);
  r[4] = f2bf(b.x); r[5] = f2bf(b.y); r[6] = f2bf(b.z); r[7] = f2bf(b.w);
  return r;
}

__global__ __launch_bounds__(256) void fc1_gemm(
    const ushort_t* __restrict__ Xf, const float* __restrict__ Wf1,
    float* __restrict__ hacc)
{
  __shared__ ushort_t As[2][4096];
  __shared__ ushort_t Bs[2][4096];
  const int tid = threadIdx.x, lane = tid & 63, wave = tid >> 6;
  const int la = lane & 15, lb = lane >> 4;
  const int f0 = blockIdx.x * 64;
  const int k0 = blockIdx.y * 4096;

  f32x4 acc[4];
#pragma unroll
  for (int i = 0; i < 4; ++i) acc[i] = (f32x4){0.f, 0.f, 0.f, 0.f};

  const ushort_t* xrow0 = Xf + (size_t)(tid >> 3) * KFC + k0 + (tid & 7) * 8;
  const ushort_t* xrow1 = Xf + (size_t)((tid + 256) >> 3) * KFC + k0 + (tid & 7) * 8;
  const int brow = tid >> 2, kseg = (tid & 3) * 16;
  const float* wrow = Wf1 + (size_t)(f0 + brow) * KFC + k0 + kseg;
  const int bwr = brow * 64 + kseg;

  float4 w0, w1, w2, w3;

  gl_lds16(xrow0, &As[0][tid * 8]);
  gl_lds16(xrow1, &As[0][(tid + 256) * 8]);
  w0 = *(const float4*)(wrow + 0);
  w1 = *(const float4*)(wrow + 4);
  w2 = *(const float4*)(wrow + 8);
  w3 = *(const float4*)(wrow + 12);
  *(u16x8*)&Bs[0][bwr]     = pack8(w0, w1);
  *(u16x8*)&Bs[0][bwr + 8] = pack8(w2, w3);
  gl_lds16(xrow0 + 64, &As[1][tid * 8]);
  gl_lds16(xrow1 + 64, &As[1][(tid + 256) * 8]);
  w0 = *(const float4*)(wrow + 64);
  w1 = *(const float4*)(wrow + 68);
  w2 = *(const float4*)(wrow + 72);
  w3 = *(const float4*)(wrow + 76);
  asm volatile("s_waitcnt lgkmcnt(0)" ::: "memory");
  __builtin_amdgcn_s_barrier();

#define FC1_MFMA(CUR) \
  { \
    _Pragma("unroll") \
    for (int kk = 0; kk < 2; ++kk) { \
      bf16x8 bfv = *(const bf16x8*)&Bs[CUR][(wave * 16 + la) * 64 + kk * 32 + lb * 8]; \
      _Pragma("unroll") \
      for (int mi = 0; mi < 4; ++mi) { \
        bf16x8 av = *(const bf16x8*)&As[CUR][(mi * 16 + la) * 64 + kk * 32 + lb * 8]; \
        acc[mi] = mfma16(av, bfv, acc[mi]); \
      } \
    } \
  }

  for (int t = 0; t < 62; ++t) {
    const int cur = t & 1, nxt = cur ^ 1;
    FC1_MFMA(cur)
    *(u16x8*)&Bs[nxt][bwr]     = pack8(w0, w1);
    *(u16x8*)&Bs[nxt][bwr + 8] = pack8(w2, w3);
    {
      const float* wp = wrow + (t + 2) * 64;
      w0 = *(const float4*)(wp + 0);
      w1 = *(const float4*)(wp + 4);
      w2 = *(const float4*)(wp + 8);
      w3 = *(const float4*)(wp + 12);
    }
    asm volatile("s_waitcnt vmcnt(4)" ::: "memory");
    asm volatile("s_waitcnt lgkmcnt(0)" ::: "memory");
    __builtin_amdgcn_s_barrier();
    gl_lds16(xrow0 + (t + 2) * 64, &As[cur][tid * 8]);
    gl_lds16(xrow1 + (t + 2) * 64, &As[cur][(tid + 256) * 8]);
  }
  {
    FC1_MFMA(0)
    *(u16x8*)&Bs[1][bwr]     = pack8(w0, w1);
    *(u16x8*)&Bs[1][bwr + 8] = pack8(w2, w3);
    asm volatile("s_waitcnt vmcnt(0)" ::: "memory");
    asm volatile("s_waitcnt lgkmcnt(0)" ::: "memory");
    __builtin_amdgcn_s_barrier();
  }
  FC1_MFMA(1)
#undef FC1_MFMA

  float* slice = hacc + (size_t)blockIdx.y * NB * NF;
#pragma unroll
  for (int mi = 0; mi < 4; ++mi) {
    int row = mi * 16 + lb * 4;
#pragma unroll
    for (int r = 0; r < 4; ++r)
      slice[(size_t)(row + r) * NF + f0 + wave * 16 + la] = acc[mi][r];
  }
}

// ---------------------------------------------------------------------------
// FC2 + bias/relu; sums the 32 fc1 k-slices. grid 64, block 256.
// ---------------------------------------------------------------------------
__global__ __launch_bounds__(256) void fc2_out(
    const float* __restrict__ hacc, const float* __restrict__ bf1,
    const float* __restrict__ Wf2, const float* __restrict__ bf2,
    float* __restrict__ out)
{
  const int b = blockIdx.x, tid = threadIdx.x;
  float a[8];
#pragma unroll
  for (int o = 0; o < 8; ++o) a[o] = 0.f;
  for (int f = tid; f < NF; f += 256) {
    float hv = bf1[f];
#pragma unroll 4
    for (int s = 0; s < KSPL; ++s)
      hv += hacc[((size_t)s * NB + b) * NF + f];
    hv = fmaxf(hv, 0.f);
#pragma unroll
    for (int o = 0; o < 8; ++o) a[o] += hv * Wf2[o * NF + f];
  }
  __shared__ float red[8][256];
#pragma unroll
  for (int o = 0; o < 8; ++o) red[o][tid] = a[o];
  __syncthreads();
  for (int s = 128; s > 0; s >>= 1) {
    if (tid < s) {
#pragma unroll
      for (int o = 0; o < 8; ++o) red[o][tid] += red[o][tid + s];
    }
    __syncthreads();
  }
  if (tid < 8) out[b * 8 + tid] = red[tid][0] + bf2[tid];
}

// ---------------------------------------------------------------------------
extern "C" void kernel_launch(void* const* d_in, const int* in_sizes, int n_in,
                              void* d_out, int out_size, void* d_ws, size_t ws_size,
                              hipStream_t stream) {
  const float* f1  = (const float*)d_in[0];
  const float* f2  = (const float*)d_in[1];
  const float* W1  = (const float*)d_in[2];
  const float* b1  = (const float*)d_in[3];
  const float* g1  = (const float*)d_in[4];
  const float* be1 = (const float*)d_in[5];
  const float* W2  = (const float*)d_in[6];
  const float* b2  = (const float*)d_in[7];
  const float* g2  = (const float*)d_in[8];
  const float* be2 = (const float*)d_in[9];
  const float* W3  = (const float*)d_in[10];
  const float* b3  = (const float*)d_in[11];
  const float* g3  = (const float*)d_in[12];
  const float* be3 = (const float*)d_in[13];
  const float* Wf1 = (const float*)d_in[14];
  const float* bf1 = (const float*)d_in[15];
  const float* Wf2 = (const float*)d_in[16];
  const float* bf2 = (const float*)d_in[17];
  float* out = (float*)d_out;

  char* ws = (char*)d_ws;
  size_t off = 0;
  auto alloc = [&](size_t bytes) -> void* {
    void* p = ws + off;
    off += (bytes + 255) & ~(size_t)255;
    return p;
  };

  // zeroed region: zero tile + BN stats
  ushort_t* zerot = (ushort_t*)alloc(256);
  float* st1  = (float*)alloc(1024 * 4);
  float* st2  = (float*)alloc(1024 * 4);
  float* st3  = (float*)alloc(1024 * 4);
  const size_t zero_bytes = off;

  float* hacc = (float*)alloc((size_t)KSPL * NB * NF * 4);  // fully written
  const size_t SZ_AT   = (size_t)NB * NP * NC * 2;
  const size_t SZ_COST = (size_t)NB * NP * KP1 * 2;
  const size_t SZ_WP1  = (size_t)9 * NOUT * KP1 * 2;
  const size_t SZ_WP23 = (size_t)9 * NOUT * 512 * 2;
  ushort_t* AT    = (ushort_t*)alloc(SZ_AT);
  ushort_t* N2T   = (ushort_t*)alloc(SZ_AT);
  float*    Cbuf  = (float*)alloc((size_t)NB * NP * NP * 4);
  ushort_t* costT = (ushort_t*)alloc(SZ_COST);   // fully written by cost_write
  ushort_t* Wp1   = (ushort_t*)alloc(SZ_WP1);
  ushort_t* Wp2   = (ushort_t*)alloc(SZ_WP23);
  ushort_t* Wp3   = (ushort_t*)alloc(SZ_WP23);
  ushort_t* Ybuf  = (ushort_t*)alloc((size_t)NROWS * NOUT * 2);
  ushort_t* Xbuf  = (ushort_t*)alloc((size_t)NROWS * NOUT * 2);
  ushort_t* Xf    = (ushort_t*)alloc((size_t)NB * KFC * 2);

  hipMemsetAsync(ws, 0, zero_bytes, stream);

  l2norm_t<<<dim3(64, 2), 1024, 0, stream>>>(f1, f2, AT, N2T);

  pack_all<<<(T1P + 2 * T23 + 255) / 256, 256, 0, stream>>>(W1, W2, W3, Wp1, Wp2, Wp3);

  corr_gemm<<<dim3(2, 2, 64), 256, 0, stream>>>(AT, N2T, Cbuf);
  cost_write<<<dim3(256, 64), 576, 0, stream>>>(Cbuf, costT);

  conv_fused<<<512, 512, 0, stream>>>(costT, Wp1, b1, Ybuf, st1, KP1, 18, 162, zerot);
  bn_apply_s<<<4096, 256, 0, stream>>>(Ybuf, st1, g1, be1, Xbuf);

  conv_fused<<<512, 512, 0, stream>>>(Xbuf, Wp2, b2, Ybuf, st2, 512, 8, 72, zerot);
  bn_apply_s<<<4096, 256, 0, stream>>>(Ybuf, st2, g2, be2, Xbuf);

  conv_fused<<<512, 512, 0, stream>>>(Xbuf, Wp3, b3, Ybuf, st3, 512, 8, 72, zerot);
  bn_apply_ts<<<dim3(8, 4, 64), 256, 0, stream>>>(Ybuf, st3, g3, be3, Xf);

  fc1_gemm<<<dim3(16, KSPL), 256, 0, stream>>>(Xf, Wf1, hacc);
  fc2_out<<<64, 256, 0, stream>>>(hacc, bf1, Wf2, bf2, out);

  (void)in_sizes; (void)n_in; (void)out_size; (void)ws_size;
}

// Round 15
// 560.153 us; speedup vs baseline: 1.0590x; 1.0590x over previous
//
#include <hip/hip_runtime.h>
#include <hip/hip_bf16.h>
#include <stdint.h>

// ---------------------------------------------------------------------------
// RegressionNet: cost-volume + 3x conv-BN-relu + 2x FC, bf16 MFMA pipeline.
// R14: REVERT to the R13 best (561us): BM=256xBN=128 conv_fused (fused BN
//      stats, 1 block/CU), pipelined fc1, reg-cached l2norm, corr+cost_write
//      cost volume, single pack launch. (BM=128 2-blk/CU experiment was +32us;
//      cooperative grid-sync was +52us — both abandoned.)
// ---------------------------------------------------------------------------

typedef unsigned short ushort_t;
typedef __attribute__((ext_vector_type(8))) short     bf16x8;
typedef __attribute__((ext_vector_type(8))) unsigned short u16x8;
typedef __attribute__((ext_vector_type(2))) unsigned short u16x2;
typedef __attribute__((ext_vector_type(4))) float     f32x4;

#define NB   64
#define NC   256
#define NP   256
#define KP1  1152
#define NOUT 512
#define NROWS 16384
#define KFC  131072
#define NF   1024
#define KSPL 32      // fc1 k-splits

__device__ __forceinline__ unsigned short f2bf(float x) {
  union { float f; unsigned u; } c; c.f = x;
  unsigned r = c.u + 0x7FFFu + ((c.u >> 16) & 1u);
  return (unsigned short)(r >> 16);
}
__device__ __forceinline__ float b2f(unsigned short u) {
  union { unsigned u; float f; } c; c.u = ((unsigned)u) << 16; return c.f;
}

__device__ __forceinline__ void gl_lds16(const void* g, void* l) {
  __builtin_amdgcn_global_load_lds(
      (const __attribute__((address_space(1))) unsigned int*)g,
      (__attribute__((address_space(3))) unsigned int*)l, 16, 0, 0);
}

__device__ __forceinline__ f32x4 mfma16(bf16x8 a, bf16x8 b, f32x4 c) {
  return __builtin_amdgcn_mfma_f32_16x16x32_bf16(a, b, c, 0, 0, 0);
}

// ---------------------------------------------------------------------------
// l2-normalize over channels; write pos-major bf16 [b][pos][c].
// grid (64,2), block 1024: 4-way channel split, values register-cached.
// ---------------------------------------------------------------------------
__global__ __launch_bounds__(1024) void l2norm_t(
    const float* __restrict__ f1, const float* __restrict__ f2,
    ushort_t* __restrict__ AT, ushort_t* __restrict__ N2T)
{
  __shared__ float red[4][256];
  const float* src = blockIdx.y ? f2 : f1;
  ushort_t*    dst = blockIdx.y ? N2T : AT;
  const int b = blockIdx.x;
  const int pos = threadIdx.x & 255, q = threadIdx.x >> 8;
  const float* sb = src + (size_t)b * NC * NP;
  float v[64];
#pragma unroll
  for (int k = 0; k < 64; ++k) v[k] = sb[(q * 64 + k) * NP + pos];
  float sq = 0.f;
#pragma unroll
  for (int k = 0; k < 64; ++k) sq += v[k] * v[k];
  red[q][pos] = sq;
  __syncthreads();
  float tot = red[0][pos] + red[1][pos] + red[2][pos] + red[3][pos];
  float sc = 1.f / fmaxf(sqrtf(tot), 1e-12f);
  ushort_t* db = dst + ((size_t)b * NP + pos) * NC;
#pragma unroll
  for (int j = 0; j < 8; ++j) {
    u16x8 pk;
#pragma unroll
    for (int k = 0; k < 8; ++k) pk[k] = f2bf(v[j * 8 + k] * sc);
    *(u16x8*)(db + q * 64 + j * 8) = pk;
  }
}

// ---------------------------------------------------------------------------
// Pack all three conv weights in one launch.
// ---------------------------------------------------------------------------
#define T1P (9 * NOUT * KP1)
#define T23 (9 * NOUT * 512)
__global__ __launch_bounds__(256) void pack_all(
    const float* __restrict__ W1, const float* __restrict__ W2,
    const float* __restrict__ W3, ushort_t* __restrict__ Wp1,
    ushort_t* __restrict__ Wp2, ushort_t* __restrict__ Wp3)
{
  int p = blockIdx.x * 256 + threadIdx.x;
  const float* W; ushort_t* Wp; int Cin, Kp, q;
  if (p < T1P)            { W = W1; Wp = Wp1; Cin = 1089; Kp = KP1; q = p; }
  else if (p < T1P + T23) { W = W2; Wp = Wp2; Cin = 512;  Kp = 512; q = p - T1P; }
  else if (p < T1P + 2 * T23) { W = W3; Wp = Wp3; Cin = 512; Kp = 512; q = p - T1P - T23; }
  else return;
  int tap = q / (NOUT * Kp);
  int rem = q - tap * (NOUT * Kp);
  int o   = rem / Kp;
  int cin = rem - o * Kp;
  float v = (cin < Cin) ? W[((size_t)o * Cin + cin) * 9 + tap] : 0.f;
  Wp[q] = f2bf(v);
}

// ---------------------------------------------------------------------------
// Correlation GEMM: C[b][p][q] = sum_c AT[b][p][c] * N2T[b][q][c].
// ---------------------------------------------------------------------------
__global__ __launch_bounds__(256) void corr_gemm(
    const ushort_t* __restrict__ AT,
    const ushort_t* __restrict__ N2T,
    float* __restrict__ C)
{
  __shared__ ushort_t As[128 * 64];
  __shared__ ushort_t Bs[128 * 64];
  const int tid = threadIdx.x, lane = tid & 63, wave = tid >> 6;
  const int wr = wave >> 1, wc = wave & 1;
  const int la = lane & 15, lb = lane >> 4;
  const int b  = blockIdx.z;
  const int m0 = blockIdx.y * 128;
  const int n0 = blockIdx.x * 128;

  f32x4 acc[4][4];
#pragma unroll
  for (int i = 0; i < 4; ++i)
#pragma unroll
    for (int j = 0; j < 4; ++j) acc[i][j] = (f32x4){0.f, 0.f, 0.f, 0.f};

  const ushort_t* srcA[4];
  const ushort_t* srcB[4];
#pragma unroll
  for (int s = 0; s < 4; ++s) {
    int idx = tid + (s << 8);
    int row = idx >> 3, c16 = idx & 7;
    srcA[s] = AT  + ((size_t)b * NP + m0 + row) * NC + c16 * 8;
    srcB[s] = N2T + ((size_t)b * NP + n0 + row) * NC + c16 * 8;
  }

  for (int kc = 0; kc < NC; kc += 64) {
#pragma unroll
    for (int s = 0; s < 4; ++s) {
      int idx = tid + (s << 8);
      gl_lds16(srcA[s] + kc, &As[idx * 8]);
      gl_lds16(srcB[s] + kc, &Bs[idx * 8]);
    }
    __syncthreads();
#pragma unroll
    for (int kk = 0; kk < 2; ++kk) {
      bf16x8 af[4], bfv[4];
#pragma unroll
      for (int mi = 0; mi < 4; ++mi)
        af[mi] = *(const bf16x8*)&As[(wr * 64 + mi * 16 + la) * 64 + kk * 32 + lb * 8];
#pragma unroll
      for (int ni = 0; ni < 4; ++ni)
        bfv[ni] = *(const bf16x8*)&Bs[(wc * 64 + ni * 16 + la) * 64 + kk * 32 + lb * 8];
#pragma unroll
      for (int mi = 0; mi < 4; ++mi)
#pragma unroll
        for (int ni = 0; ni < 4; ++ni)
          acc[mi][ni] = mfma16(af[mi], bfv[ni], acc[mi][ni]);
    }
    __syncthreads();
  }

#pragma unroll
  for (int ni = 0; ni < 4; ++ni) {
    int col = n0 + wc * 64 + ni * 16 + la;
#pragma unroll
    for (int mi = 0; mi < 4; ++mi) {
      int p = m0 + wr * 64 + mi * 16 + lb * 4;
#pragma unroll
      for (int r = 0; r < 4; ++r)
        C[((size_t)b * NP + p + r) * NP + col] = acc[mi][ni][r];
    }
  }
}

// ---------------------------------------------------------------------------
// Cost write: expand C[b][ij][256] -> costT[b][ij][1152] (gather + scale +
// leaky relu; zeros elsewhere). grid (256, 64), block 576.
// ---------------------------------------------------------------------------
__global__ __launch_bounds__(576) void cost_write(
    const float* __restrict__ C, ushort_t* __restrict__ costT)
{
  __shared__ float row[256];
  const int ij = blockIdx.x, b = blockIdx.y, tid = threadIdx.x;
  const float* cr = C + ((size_t)b * NP + ij) * NP;
  if (tid < 256) row[tid] = cr[tid];
  __syncthreads();
  const int i = ij >> 4, j = ij & 15;
  const int d0 = tid * 2;
  u16x2 pk;
#pragma unroll
  for (int q = 0; q < 2; ++q) {
    int dd = d0 + q;
    int dy = dd / 33;
    int dx = dd - dy * 33;
    int oi = dy + i - 16, oj = dx + j - 16;
    float v = 0.f;
    if (((unsigned)oi < 16u) & ((unsigned)oj < 16u))
      v = row[oi * 16 + oj] * (1.f / 256.f);
    v = v > 0.f ? v : 0.01f * v;
    pk[q] = f2bf(v);
  }
  *(u16x2*)(costT + ((size_t)b * NP + ij) * KP1 + d0) = pk;
}

// ---------------------------------------------------------------------------
// Conv (all layers): BM=256, BN=128, NO K-split, fused BN stats. Block 512 =
// 8 waves (2M x 4N), per-wave 128x32 (acc[8][2]). LDS dbuf 2x(A 32KB+B 16KB).
// 2 phases/tile, counted vmcnt (4/2, never 0 mid-loop). Epilogue: y=acc+bias
// -> bf16 Y + shfl-reduced stats atomics. grid 256 (XCD-swizzled).
// ---------------------------------------------------------------------------
__global__ __launch_bounds__(512, 1) void conv_fused(
    const ushort_t* __restrict__ X, const ushort_t* __restrict__ Wp,
    const float* __restrict__ bias, ushort_t* __restrict__ Y,
    float* __restrict__ st, const int K, const int TPT, const int NT,
    const ushort_t* __restrict__ zerot)
{
  __shared__ ushort_t lds[2 * 24576];   // per buf: A[0,16384) B[16384,24576)
  const int tid = threadIdx.x;
  const int lane = tid & 63, wave = tid >> 6;
  const int wr = wave >> 2, wc = wave & 3;
  const int la = lane & 15, lb = lane >> 4;

  const int bid = blockIdx.x;
  const int L = ((bid & 7) << 5) + (bid >> 3);
  const int b = L >> 2;
  const int n0 = (L & 3) << 7;

  int amask[4];
  const ushort_t* abase[4];
  const ushort_t* bbase[2];
#pragma unroll
  for (int s = 0; s < 4; ++s) {
    int idx = tid + (s << 9);
    int ks = idx & 7, loc = (idx >> 3) & 63;
    int rA = ((s & 1) << 7) + ((s >> 1) << 6) + loc;
    int i = rA >> 4, j = rA & 15;
    int m = 0;
#pragma unroll
    for (int tap = 0; tap < 9; ++tap) {
      int i2 = i + tap / 3 - 1, j2 = j + tap % 3 - 1;
      if (((unsigned)i2 < 16u) & ((unsigned)j2 < 16u)) m |= 1 << tap;
    }
    amask[s] = m;
    abase[s] = X + (size_t)(b * NP + rA) * K + ((ks ^ (rA & 7)) << 3);
  }
#pragma unroll
  for (int s = 0; s < 2; ++s) {
    int idx = tid + (s << 9);
    int ks = idx & 7, loc = (idx >> 3) & 63;
    int rB = (s << 6) + loc;
    bbase[s] = Wp + (size_t)(n0 + rB) * K + ((ks ^ (rB & 7)) << 3);
  }

  const int ck0 = ((0 + lb) ^ (la & 7)) << 3;
  const int ck1 = ((4 + lb) ^ (la & 7)) << 3;
  const int a_base = wr * 4096 + la * 64;
  const int b_off  = 16384 + (wc * 32 + la) * 64;

  f32x4 acc[8][2];
#pragma unroll
  for (int i = 0; i < 8; ++i)
#pragma unroll
    for (int j = 0; j < 2; ++j) acc[i][j] = (f32x4){0.f, 0.f, 0.f, 0.f};

  auto tile_par = [&](int tg, int& toffA, size_t& wtap, int& tap) {
    tap = tg / TPT;
    int kc = (tg - tap * TPT) << 6;
    int ty = tap / 3;
    toffA = (ty * 16 + (tap - 3 * ty) - 17) * K + kc;
    wtap  = (size_t)tap * NOUT * K + kc;
  };

#define FSTAGE_A(S) { const ushort_t* gp = ((amask[S] >> tapN) & 1) ? abase[S] + toffN : zerot; \
                      gl_lds16(gp, &bufn[(tid + ((S) << 9)) * 8]); }
#define FSTAGE_B(S) gl_lds16(bbase[S] + wtapN, &bufn[16384 + (tid + ((S) << 9)) * 8]);
#define FREAD_A03() \
  Af[0][0] = *(const bf16x8*)&buf[a_base + 0    + ck0]; Af[0][1] = *(const bf16x8*)&buf[a_base + 0    + ck1]; \
  Af[1][0] = *(const bf16x8*)&buf[a_base + 1024 + ck0]; Af[1][1] = *(const bf16x8*)&buf[a_base + 1024 + ck1]; \
  Af[2][0] = *(const bf16x8*)&buf[a_base + 2048 + ck0]; Af[2][1] = *(const bf16x8*)&buf[a_base + 2048 + ck1]; \
  Af[3][0] = *(const bf16x8*)&buf[a_base + 3072 + ck0]; Af[3][1] = *(const bf16x8*)&buf[a_base + 3072 + ck1];
#define FREAD_A47() \
  Af[0][0] = *(const bf16x8*)&buf[a_base + 8192 + 0    + ck0]; Af[0][1] = *(const bf16x8*)&buf[a_base + 8192 + 0    + ck1]; \
  Af[1][0] = *(const bf16x8*)&buf[a_base + 8192 + 1024 + ck0]; Af[1][1] = *(const bf16x8*)&buf[a_base + 8192 + 1024 + ck1]; \
  Af[2][0] = *(const bf16x8*)&buf[a_base + 8192 + 2048 + ck0]; Af[2][1] = *(const bf16x8*)&buf[a_base + 8192 + 2048 + ck1]; \
  Af[3][0] = *(const bf16x8*)&buf[a_base + 8192 + 3072 + ck0]; Af[3][1] = *(const bf16x8*)&buf[a_base + 8192 + 3072 + ck1];
#define FREAD_B() \
  Bf[0][0] = *(const bf16x8*)&buf[b_off + 0    + ck0]; Bf[0][1] = *(const bf16x8*)&buf[b_off + 0    + ck1]; \
  Bf[1][0] = *(const bf16x8*)&buf[b_off + 1024 + ck0]; Bf[1][1] = *(const bf16x8*)&buf[b_off + 1024 + ck1];
#define FMFMA(AB) \
  acc[(AB)+0][0] = mfma16(Af[0][0], Bf[0][0], acc[(AB)+0][0]); \
  acc[(AB)+0][1] = mfma16(Af[0][0], Bf[1][0], acc[(AB)+0][1]); \
  acc[(AB)+1][0] = mfma16(Af[1][0], Bf[0][0], acc[(AB)+1][0]); \
  acc[(AB)+1][1] = mfma16(Af[1][0], Bf[1][0], acc[(AB)+1][1]); \
  acc[(AB)+2][0] = mfma16(Af[2][0], Bf[0][0], acc[(AB)+2][0]); \
  acc[(AB)+2][1] = mfma16(Af[2][0], Bf[1][0], acc[(AB)+2][1]); \
  acc[(AB)+3][0] = mfma16(Af[3][0], Bf[0][0], acc[(AB)+3][0]); \
  acc[(AB)+3][1] = mfma16(Af[3][0], Bf[1][0], acc[(AB)+3][1]); \
  acc[(AB)+0][0] = mfma16(Af[0][1], Bf[0][1], acc[(AB)+0][0]); \
  acc[(AB)+0][1] = mfma16(Af[0][1], Bf[1][1], acc[(AB)+0][1]); \
  acc[(AB)+1][0] = mfma16(Af[1][1], Bf[0][1], acc[(AB)+1][0]); \
  acc[(AB)+1][1] = mfma16(Af[1][1], Bf[1][1], acc[(AB)+1][1]); \
  acc[(AB)+2][0] = mfma16(Af[2][1], Bf[0][1], acc[(AB)+2][0]); \
  acc[(AB)+2][1] = mfma16(Af[2][1], Bf[1][1], acc[(AB)+2][1]); \
  acc[(AB)+3][0] = mfma16(Af[3][1], Bf[0][1], acc[(AB)+3][0]); \
  acc[(AB)+3][1] = mfma16(Af[3][1], Bf[1][1], acc[(AB)+3][1]);

  // prologue: stage tile 0 (A0 A1 B0 B1 A2 A3); leave A2A3 in flight
  {
    ushort_t* bufn = &lds[0];
    int tapN, toffN; size_t wtapN;
    tile_par(0, toffN, wtapN, tapN);
    FSTAGE_A(0) FSTAGE_A(1) FSTAGE_B(0) FSTAGE_B(1) FSTAGE_A(2) FSTAGE_A(3)
  }
  asm volatile("s_waitcnt vmcnt(2)" ::: "memory");
  __builtin_amdgcn_s_barrier();

  for (int t = 0; t < NT - 1; ++t) {
    const ushort_t* buf = &lds[(t & 1) * 24576];
    ushort_t* bufn = &lds[((t + 1) & 1) * 24576];
    int tapN, toffN; size_t wtapN;
    tile_par(t + 1, toffN, wtapN, tapN);
    bf16x8 Af[4][2], Bf[2][2];

    FREAD_A03()
    FREAD_B()
    FSTAGE_A(0) FSTAGE_A(1) FSTAGE_B(0) FSTAGE_B(1)
    asm volatile("s_waitcnt vmcnt(4)" ::: "memory");
    __builtin_amdgcn_s_barrier();
    asm volatile("s_waitcnt lgkmcnt(0)" ::: "memory");
    __builtin_amdgcn_sched_barrier(0);
    __builtin_amdgcn_s_setprio(1);
    FMFMA(0)
    __builtin_amdgcn_s_setprio(0);

    FREAD_A47()
    FSTAGE_A(2) FSTAGE_A(3)
    asm volatile("s_waitcnt vmcnt(2)" ::: "memory");
    __builtin_amdgcn_s_barrier();
    asm volatile("s_waitcnt lgkmcnt(0)" ::: "memory");
    __builtin_amdgcn_sched_barrier(0);
    __builtin_amdgcn_s_setprio(1);
    FMFMA(4)
    __builtin_amdgcn_s_setprio(0);
  }

  // tail tile
  {
    const ushort_t* buf = &lds[((NT - 1) & 1) * 24576];
    bf16x8 Af[4][2], Bf[2][2];
    FREAD_A03()
    FREAD_B()
    asm volatile("s_waitcnt vmcnt(0)" ::: "memory");
    __builtin_amdgcn_s_barrier();
    asm volatile("s_waitcnt lgkmcnt(0)" ::: "memory");
    __builtin_amdgcn_sched_barrier(0);
    FMFMA(0)
    FREAD_A47()
    asm volatile("s_waitcnt lgkmcnt(0)" ::: "memory");
    __builtin_amdgcn_sched_barrier(0);
    FMFMA(4)
  }

  // epilogue: bias + bf16 Y + fused BN stats
#pragma unroll
  for (int ni = 0; ni < 2; ++ni) {
    int col = n0 + wc * 32 + ni * 16 + la;
    float bv = bias[col];
    float s = 0.f, qq = 0.f;
#pragma unroll
    for (int mi = 0; mi < 8; ++mi) {
      int row = b * NP + wr * 128 + mi * 16 + lb * 4;
#pragma unroll
      for (int r = 0; r < 4; ++r) {
        float v = acc[mi][ni][r] + bv;
        Y[(size_t)(row + r) * NOUT + col] = f2bf(v);
        s += v; qq += v * v;
      }
    }
    s  += __shfl_xor(s, 16);  s  += __shfl_xor(s, 32);
    qq += __shfl_xor(qq, 16); qq += __shfl_xor(qq, 32);
    if (lb == 0) {
      atomicAdd(&st[col], s);
      atomicAdd(&st[512 + col], qq);
    }
  }
#undef FSTAGE_A
#undef FSTAGE_B
#undef FREAD_A03
#undef FREAD_A47
#undef FREAD_B
#undef FMFMA
}

// ---------------------------------------------------------------------------
// BN apply (single Y) + relu + bf16, [m][c]. grid 4096, block 256.
// ---------------------------------------------------------------------------
__global__ __launch_bounds__(256) void bn_apply_s(
    const ushort_t* __restrict__ Y, const float* __restrict__ st,
    const float* __restrict__ g, const float* __restrict__ be,
    ushort_t* __restrict__ Xo)
{
  const size_t idx = (size_t)blockIdx.x * 256 + threadIdx.x;
  u16x8 a = *(const u16x8*)(Y + idx * 8);
  const int c0 = (int)((idx * 8) & 511);
  u16x8 pk;
#pragma unroll
  for (int q = 0; q < 8; ++q) {
    int cc = c0 + q;
    float y = b2f(a[q]);
    float mu  = st[cc] * (1.f / 16384.f);
    float var = st[512 + cc] * (1.f / 16384.f) - mu * mu;
    float s = rsqrtf(var + 1e-5f) * g[cc];
    pk[q] = f2bf(fmaxf((y - mu) * s + be[cc], 0.f));
  }
  *(u16x8*)(Xo + idx * 8) = pk;
}

// ---------------------------------------------------------------------------
// BN apply (single Y) + relu + bf16, transposed to Xf[b][c*256+ij].
// ---------------------------------------------------------------------------
__global__ __launch_bounds__(256) void bn_apply_ts(
    const ushort_t* __restrict__ Y, const float* __restrict__ st,
    const float* __restrict__ g, const float* __restrict__ be,
    ushort_t* __restrict__ Xf)
{
  __shared__ ushort_t T[64][65];
  const int c0  = blockIdx.x * 64;
  const int ij0 = blockIdx.y * 64;
  const int b   = blockIdx.z;
  const int tid = threadIdx.x;

#pragma unroll
  for (int it = 0; it < 16; ++it) {
    int e = it * 256 + tid;
    int ij = e >> 6, c = e & 63;
    int cg = c0 + c;
    float y = b2f(Y[((size_t)(b * NP + ij0 + ij)) * NOUT + cg]);
    float mu  = st[cg] * (1.f / 16384.f);
    float var = st[512 + cg] * (1.f / 16384.f) - mu * mu;
    float s = rsqrtf(var + 1e-5f) * g[cg];
    T[ij][c] = f2bf(fmaxf((y - mu) * s + be[cg], 0.f));
  }
  __syncthreads();
#pragma unroll
  for (int it = 0; it < 16; ++it) {
    int e = it * 256 + tid;
    int cr = e >> 6, ijc = e & 63;
    Xf[(size_t)b * KFC + (size_t)(c0 + cr) * NP + ij0 + ijc] = T[ijc][cr];
  }
}

// ---------------------------------------------------------------------------
// FC1: (64 x 131072) bf16 @ (1024 x 131072)^T, split-K slice stores.
// Software-pipelined. grid (16, 32), block 256.
// ---------------------------------------------------------------------------
__device__ __forceinline__ u16x8 pack8(float4 a, float4 b) {
  u16x8 r;
  r[0] = f2bf(a.x); r[1] = f2bf(a.y); r[2] = f2bf(a.z); r[3] = f2bf(a.w);
  r[4] = f2bf(b.x); r[5] = f2bf(b.y); r[6] = f2bf(b.z); r[7] = f2bf(b.w);
  return r;
}

__global__ __launch_bounds__(256) void fc1_gemm(
    const ushort_t* __restrict__ Xf, const float* __restrict__ Wf1,
    float* __restrict__ hacc)
{
  __shared__ ushort_t As[2][4096];
  __shared__ ushort_t Bs[2][4096];
  const int tid = threadIdx.x, lane = tid & 63, wave = tid >> 6;
  const int la = lane & 15, lb = lane >> 4;
  const int f0 = blockIdx.x * 64;
  const int k0 = blockIdx.y * 4096;

  f32x4 acc[4];
#pragma unroll
  for (int i = 0; i < 4; ++i) acc[i] = (f32x4){0.f, 0.f, 0.f, 0.f};

  const ushort_t* xrow0 = Xf + (size_t)(tid >> 3) * KFC + k0 + (tid & 7) * 8;
  const ushort_t* xrow1 = Xf + (size_t)((tid + 256) >> 3) * KFC + k0 + (tid & 7) * 8;
  const int brow = tid >> 2, kseg = (tid & 3) * 16;
  const float* wrow = Wf1 + (size_t)(f0 + brow) * KFC + k0 + kseg;
  const int bwr = brow * 64 + kseg;

  float4 w0, w1, w2, w3;

  gl_lds16(xrow0, &As[0][tid * 8]);
  gl_lds16(xrow1, &As[0][(tid + 256) * 8]);
  w0 = *(const float4*)(wrow + 0);
  w1 = *(const float4*)(wrow + 4);
  w2 = *(const float4*)(wrow + 8);
  w3 = *(const float4*)(wrow + 12);
  *(u16x8*)&Bs[0][bwr]     = pack8(w0, w1);
  *(u16x8*)&Bs[0][bwr + 8] = pack8(w2, w3);
  gl_lds16(xrow0 + 64, &As[1][tid * 8]);
  gl_lds16(xrow1 + 64, &As[1][(tid + 256) * 8]);
  w0 = *(const float4*)(wrow + 64);
  w1 = *(const float4*)(wrow + 68);
  w2 = *(const float4*)(wrow + 72);
  w3 = *(const float4*)(wrow + 76);
  asm volatile("s_waitcnt lgkmcnt(0)" ::: "memory");
  __builtin_amdgcn_s_barrier();

#define FC1_MFMA(CUR) \
  { \
    _Pragma("unroll") \
    for (int kk = 0; kk < 2; ++kk) { \
      bf16x8 bfv = *(const bf16x8*)&Bs[CUR][(wave * 16 + la) * 64 + kk * 32 + lb * 8]; \
      _Pragma("unroll") \
      for (int mi = 0; mi < 4; ++mi) { \
        bf16x8 av = *(const bf16x8*)&As[CUR][(mi * 16 + la) * 64 + kk * 32 + lb * 8]; \
        acc[mi] = mfma16(av, bfv, acc[mi]); \
      } \
    } \
  }

  for (int t = 0; t < 62; ++t) {
    const int cur = t & 1, nxt = cur ^ 1;
    FC1_MFMA(cur)
    *(u16x8*)&Bs[nxt][bwr]     = pack8(w0, w1);
    *(u16x8*)&Bs[nxt][bwr + 8] = pack8(w2, w3);
    {
      const float* wp = wrow + (t + 2) * 64;
      w0 = *(const float4*)(wp + 0);
      w1 = *(const float4*)(wp + 4);
      w2 = *(const float4*)(wp + 8);
      w3 = *(const float4*)(wp + 12);
    }
    asm volatile("s_waitcnt vmcnt(4)" ::: "memory");
    asm volatile("s_waitcnt lgkmcnt(0)" ::: "memory");
    __builtin_amdgcn_s_barrier();
    gl_lds16(xrow0 + (t + 2) * 64, &As[cur][tid * 8]);
    gl_lds16(xrow1 + (t + 2) * 64, &As[cur][(tid + 256) * 8]);
  }
  {
    FC1_MFMA(0)
    *(u16x8*)&Bs[1][bwr]     = pack8(w0, w1);
    *(u16x8*)&Bs[1][bwr + 8] = pack8(w2, w3);
    asm volatile("s_waitcnt vmcnt(0)" ::: "memory");
    asm volatile("s_waitcnt lgkmcnt(0)" ::: "memory");
    __builtin_amdgcn_s_barrier();
  }
  FC1_MFMA(1)
#undef FC1_MFMA

  float* slice = hacc + (size_t)blockIdx.y * NB * NF;
#pragma unroll
  for (int mi = 0; mi < 4; ++mi) {
    int row = mi * 16 + lb * 4;
#pragma unroll
    for (int r = 0; r < 4; ++r)
      slice[(size_t)(row + r) * NF + f0 + wave * 16 + la] = acc[mi][r];
  }
}

// ---------------------------------------------------------------------------
// FC2 + bias/relu; sums the 32 fc1 k-slices. grid 64, block 256.
// ---------------------------------------------------------------------------
__global__ __launch_bounds__(256) void fc2_out(
    const float* __restrict__ hacc, const float* __restrict__ bf1,
    const float* __restrict__ Wf2, const float* __restrict__ bf2,
    float* __restrict__ out)
{
  const int b = blockIdx.x, tid = threadIdx.x;
  float a[8];
#pragma unroll
  for (int o = 0; o < 8; ++o) a[o] = 0.f;
  for (int f = tid; f < NF; f += 256) {
    float hv = bf1[f];
#pragma unroll 4
    for (int s = 0; s < KSPL; ++s)
      hv += hacc[((size_t)s * NB + b) * NF + f];
    hv = fmaxf(hv, 0.f);
#pragma unroll
    for (int o = 0; o < 8; ++o) a[o] += hv * Wf2[o * NF + f];
  }
  __shared__ float red[8][256];
#pragma unroll
  for (int o = 0; o < 8; ++o) red[o][tid] = a[o];
  __syncthreads();
  for (int s = 128; s > 0; s >>= 1) {
    if (tid < s) {
#pragma unroll
      for (int o = 0; o < 8; ++o) red[o][tid] += red[o][tid + s];
    }
    __syncthreads();
  }
  if (tid < 8) out[b * 8 + tid] = red[tid][0] + bf2[tid];
}

// ---------------------------------------------------------------------------
extern "C" void kernel_launch(void* const* d_in, const int* in_sizes, int n_in,
                              void* d_out, int out_size, void* d_ws, size_t ws_size,
                              hipStream_t stream) {
  const float* f1  = (const float*)d_in[0];
  const float* f2  = (const float*)d_in[1];
  const float* W1  = (const float*)d_in[2];
  const float* b1  = (const float*)d_in[3];
  const float* g1  = (const float*)d_in[4];
  const float* be1 = (const float*)d_in[5];
  const float* W2  = (const float*)d_in[6];
  const float* b2  = (const float*)d_in[7];
  const float* g2  = (const float*)d_in[8];
  const float* be2 = (const float*)d_in[9];
  const float* W3  = (const float*)d_in[10];
  const float* b3  = (const float*)d_in[11];
  const float* g3  = (const float*)d_in[12];
  const float* be3 = (const float*)d_in[13];
  const float* Wf1 = (const float*)d_in[14];
  const float* bf1 = (const float*)d_in[15];
  const float* Wf2 = (const float*)d_in[16];
  const float* bf2 = (const float*)d_in[17];
  float* out = (float*)d_out;

  char* ws = (char*)d_ws;
  size_t off = 0;
  auto alloc = [&](size_t bytes) -> void* {
    void* p = ws + off;
    off += (bytes + 255) & ~(size_t)255;
    return p;
  };

  // zeroed region: zero tile + BN stats
  ushort_t* zerot = (ushort_t*)alloc(256);
  float* st1  = (float*)alloc(1024 * 4);
  float* st2  = (float*)alloc(1024 * 4);
  float* st3  = (float*)alloc(1024 * 4);
  const size_t zero_bytes = off;

  float* hacc = (float*)alloc((size_t)KSPL * NB * NF * 4);  // fully written
  const size_t SZ_AT   = (size_t)NB * NP * NC * 2;
  const size_t SZ_COST = (size_t)NB * NP * KP1 * 2;
  const size_t SZ_WP1  = (size_t)9 * NOUT * KP1 * 2;
  const size_t SZ_WP23 = (size_t)9 * NOUT * 512 * 2;
  ushort_t* AT    = (ushort_t*)alloc(SZ_AT);
  ushort_t* N2T   = (ushort_t*)alloc(SZ_AT);
  float*    Cbuf  = (float*)alloc((size_t)NB * NP * NP * 4);
  ushort_t* costT = (ushort_t*)alloc(SZ_COST);   // fully written by cost_write
  ushort_t* Wp1   = (ushort_t*)alloc(SZ_WP1);
  ushort_t* Wp2   = (ushort_t*)alloc(SZ_WP23);
  ushort_t* Wp3   = (ushort_t*)alloc(SZ_WP23);
  ushort_t* Ybuf  = (ushort_t*)alloc((size_t)NROWS * NOUT * 2);
  ushort_t* Xbuf  = (ushort_t*)alloc((size_t)NROWS * NOUT * 2);
  ushort_t* Xf    = (ushort_t*)alloc((size_t)NB * KFC * 2);

  hipMemsetAsync(ws, 0, zero_bytes, stream);

  l2norm_t<<<dim3(64, 2), 1024, 0, stream>>>(f1, f2, AT, N2T);

  pack_all<<<(T1P + 2 * T23 + 255) / 256, 256, 0, stream>>>(W1, W2, W3, Wp1, Wp2, Wp3);

  corr_gemm<<<dim3(2, 2, 64), 256, 0, stream>>>(AT, N2T, Cbuf);
  cost_write<<<dim3(256, 64), 576, 0, stream>>>(Cbuf, costT);

  conv_fused<<<256, 512, 0, stream>>>(costT, Wp1, b1, Ybuf, st1, KP1, 18, 162, zerot);
  bn_apply_s<<<4096, 256, 0, stream>>>(Ybuf, st1, g1, be1, Xbuf);

  conv_fused<<<256, 512, 0, stream>>>(Xbuf, Wp2, b2, Ybuf, st2, 512, 8, 72, zerot);
  bn_apply_s<<<4096, 256, 0, stream>>>(Ybuf, st2, g2, be2, Xbuf);

  conv_fused<<<256, 512, 0, stream>>>(Xbuf, Wp3, b3, Ybuf, st3, 512, 8, 72, zerot);
  bn_apply_ts<<<dim3(8, 4, 64), 256, 0, stream>>>(Ybuf, st3, g3, be3, Xf);

  fc1_gemm<<<dim3(16, KSPL), 256, 0, stream>>>(Xf, Wf1, hacc);
  fc2_out<<<64, 256, 0, stream>>>(hacc, bf1, Wf2, bf2, out);

  (void)in_sizes; (void)n_in; (void)out_size; (void)ws_size;
}